// Round 6
// baseline (1959.050 us; speedup 1.0000x reference)
//
#include <hip/hip_runtime.h>

typedef unsigned short u16;
typedef unsigned int u32;
typedef __attribute__((ext_vector_type(8))) short bf16x8;
typedef __attribute__((ext_vector_type(4))) float f32x4;

#define T_STEPS 512
#define FEAT 128
#define H1 200
#define G1 800
#define G1P 832
#define KP 224
#define XG_T_BYTES 425984   // 256 * 832 * 2
#define XG_WG_BYTES 6656    // 4 * 832 * 2

// async global->LDS, 16B/lane; LDS dest must be wave-uniform base (+lane*16 in HW)
#define G2L16(g, lp) __builtin_amdgcn_global_load_lds( \
    (const __attribute__((address_space(1))) void*)(g), \
    (__attribute__((address_space(3))) void*)(lp), 16, 0, 0)

__device__ __forceinline__ u16 f2bf(float x) {
    u32 u = __float_as_uint(x);
    u = (u + 0x7fffu + ((u >> 16) & 1u)) >> 16;
    return (u16)u;
}
__device__ __forceinline__ float bfu2f(u32 u) { return __uint_as_float(u << 16); }

__device__ __forceinline__ float sig2(float x) {
    return __builtin_amdgcn_rcpf(1.f + __builtin_amdgcn_exp2f(-1.442695041f * x));
}
__device__ __forceinline__ float tanh2(float x) {
    return 1.f - 2.f * __builtin_amdgcn_rcpf(1.f + __builtin_amdgcn_exp2f(2.885390082f * x));
}

// ---------------------------------------------------------------------------
// Kernel 1: repack weights to bf16 MFMA B-fragment order + fused bias.
// whhf: [tile*7+kt][lane][8], tile in [0,50); wihf: [ntg*4+kt][lane][8]
// ---------------------------------------------------------------------------
__global__ void repack_k(const float* __restrict__ wih1, const float* __restrict__ whh1,
                         const float* __restrict__ bih1, const float* __restrict__ bhh1,
                         u16* __restrict__ wihf, u16* __restrict__ whhf, float* __restrict__ b1p) {
    int id = blockIdx.x * 256 + threadIdx.x;
    if (id < G1P) b1p[id] = (id < G1) ? (bih1[id] + bhh1[id]) : 0.f;
    if (id < 22400) { // 50*7*64 lane-slots for whh
        int l = id & 63, fi = id >> 6;
        int kt = fi % 7, tile = fi / 7;
        int n = tile * 16 + (l & 15);
        int kb = kt * 32 + (l >> 4) * 8;
        u16 o[8];
#pragma unroll
        for (int j = 0; j < 8; ++j) {
            int k = kb + j;
            float v = (k < H1) ? whh1[n * H1 + k] : 0.f;
            o[j] = f2bf(v);
        }
        uint4 pk;
        pk.x = (u32)o[0] | ((u32)o[1] << 16);
        pk.y = (u32)o[2] | ((u32)o[3] << 16);
        pk.z = (u32)o[4] | ((u32)o[5] << 16);
        pk.w = (u32)o[6] | ((u32)o[7] << 16);
        *(uint4*)(whhf + (size_t)id * 8) = pk;
    }
    int id2 = id - 22400;
    if (id2 >= 0 && id2 < 13312) { // 52*4*64 lane-slots for wih
        int l = id2 & 63, fi = id2 >> 6;
        int kt = fi & 3, ntg = fi >> 2;
        int n = ntg * 16 + (l & 15);
        int kb = kt * 32 + (l >> 4) * 8;
        u16 o[8];
#pragma unroll
        for (int j = 0; j < 8; ++j) {
            int k = kb + j;
            float v = (n < G1) ? wih1[n * FEAT + k] : 0.f;
            o[j] = f2bf(v);
        }
        uint4 pk;
        pk.x = (u32)o[0] | ((u32)o[1] << 16);
        pk.y = (u32)o[2] | ((u32)o[3] << 16);
        pk.z = (u32)o[4] | ((u32)o[5] << 16);
        pk.w = (u32)o[6] | ((u32)o[7] << 16);
        *(uint4*)(wihf + (size_t)id2 * 8) = pk;
    }
}

// ---------------------------------------------------------------------------
// Kernel 2: xg = X @ W_ih1^T + bias, bf16, natural layout xg[t][b][col 0..831]
// (verbatim — verified)
// ---------------------------------------------------------------------------
__global__ __launch_bounds__(256, 1) void xg_gemm(const float* __restrict__ X,
                                                  const u16* __restrict__ wihf,
                                                  const float* __restrict__ b1p,
                                                  u16* __restrict__ xg) {
    __shared__ u16 xs[64 * 128];
    int tid = threadIdx.x, wg = blockIdx.x;
    int l = tid & 63, wv = tid >> 6;
    int arow = l & 15, khi = l >> 4;

    const float4* Xv = (const float4*)(X + (size_t)wg * 64 * 128);
#pragma unroll
    for (int i = 0; i < 8; ++i) {
        int idx = tid + i * 256;
        float4 v = Xv[idx];
        int row = idx >> 5;
        int col = (idx & 31) * 4;
        uint2 pk;
        pk.x = (u32)f2bf(v.x) | ((u32)f2bf(v.y) << 16);
        pk.y = (u32)f2bf(v.z) | ((u32)f2bf(v.w) << 16);
        int byteo = (row * 256 + col * 2) ^ ((row & 7) << 4);
        *(uint2*)((char*)xs + byteo) = pk;
    }
    __syncthreads();

    f32x4 acc[4][13];
#pragma unroll
    for (int mt = 0; mt < 4; ++mt)
#pragma unroll
        for (int nt = 0; nt < 13; ++nt) acc[mt][nt] = (f32x4){0.f, 0.f, 0.f, 0.f};

#pragma unroll
    for (int kt = 0; kt < 4; ++kt) {
        bf16x8 wfr[13];
#pragma unroll
        for (int nt = 0; nt < 13; ++nt) {
            int ntg = wv * 13 + nt;
            wfr[nt] = *(const bf16x8*)(wihf + ((size_t)(ntg * 4 + kt) * 64 + l) * 8);
        }
#pragma unroll
        for (int mt = 0; mt < 4; ++mt) {
            int row = mt * 16 + arow;
            int byteo = (row * 256 + kt * 64 + khi * 16) ^ ((row & 7) << 4);
            bf16x8 a = *(const bf16x8*)((const char*)xs + byteo);
#pragma unroll
            for (int nt = 0; nt < 13; ++nt)
                acc[mt][nt] = __builtin_amdgcn_mfma_f32_16x16x32_bf16(a, wfr[nt], acc[mt][nt], 0, 0, 0);
        }
    }

    int t = wg >> 2;
#pragma unroll
    for (int nt = 0; nt < 13; ++nt) {
        int ntg = wv * 13 + nt;
        int colg = ntg * 16 + arow;
        float bias = b1p[colg];
#pragma unroll
        for (int mt = 0; mt < 4; ++mt) {
#pragma unroll
            for (int r = 0; r < 4; ++r) {
                int bg = (wg & 3) * 64 + mt * 16 + khi * 4 + r;
                xg[((size_t)t * 256 + bg) * G1P + colg] = f2bf(acc[mt][nt][r] + bias);
            }
        }
    }
}

// ---------------------------------------------------------------------------
// Kernel 3: persistent fused 2-layer LSTM. 64 WGs x 256 threads (4 waves,
// 1 wave/SIMD, 512 unified regs/wave). W_hh1 pinned in AGPRs via asm-output
// keepalive (cannot be remat'd as a load); INTRINSIC MFMA reads B directly
// from AGPR (AV operand class) -> compiler handles all MFMA hazards.
// Tiles (13,13,12,12); wave3 also owns layer-2 in-register. 2 barriers/step.
// ---------------------------------------------------------------------------
#define LDHB(KT) (*(const bf16x8*)((const char*)hbuf + ((arow * 448 + (KT) * 64 + khi * 16) ^ ((arow & 7) << 4))))

template<int CNT, bool L2O>
__device__ __forceinline__ void lstm_body(
    int tile0, int wv, int l, int mw,
    const u16* __restrict__ xg, const u16* __restrict__ whhf,
    const float* __restrict__ w_ih2, const float* __restrict__ w_hh2,
    const float* __restrict__ b_ih2, const float* __restrict__ b_hh2,
    float* __restrict__ out, u16* hbuf, float* gbuf, u16* xgs)
{
    const int arow = l & 15, khi = l >> 4;
    const f32x4 fz = {0.f, 0.f, 0.f, 0.f};

    // persistent W_hh B-fragments, pinned in AGPRs. The asm output is the SSA
    // value consumed by every MFMA -> allocator cannot rematerialize the load.
    bf16x8 wf[CNT][7];
#pragma unroll
    for (int nt = 0; nt < CNT; ++nt)
#pragma unroll
        for (int kt = 0; kt < 7; ++kt) {
            wf[nt][kt] = *(const bf16x8*)(whhf + ((size_t)((tile0 + nt) * 7 + kt) * 64 + l) * 8);
            asm volatile("" : "+a"(wf[nt][kt]));
        }

    // layer-2 state (wave 3 only; DCE'd elsewhere)
    bf16x8 wf2[7];
    float wh[4][3], b2l[4], h2p[4], c2[4];
    f32x4 acc2 = fz;
    if constexpr (L2O) {
#pragma unroll
        for (int kt = 0; kt < 7; ++kt) {
            u16 o[8];
#pragma unroll
            for (int j = 0; j < 8; ++j) {
                int k = kt * 32 + khi * 8 + j;
                o[j] = (arow < 12 && k < H1) ? f2bf(w_ih2[arow * H1 + k]) : (u16)0;
            }
            uint4 pk;
            pk.x = (u32)o[0] | ((u32)o[1] << 16);
            pk.y = (u32)o[2] | ((u32)o[3] << 16);
            pk.z = (u32)o[4] | ((u32)o[5] << 16);
            pk.w = (u32)o[6] | ((u32)o[7] << 16);
            wf2[kt] = *(bf16x8*)&pk;
            asm volatile("" : "+a"(wf2[kt]));
        }
        int hs = (l < 3) ? l : 0;
#pragma unroll
        for (int g = 0; g < 4; ++g) {
#pragma unroll
            for (int q = 0; q < 3; ++q) wh[g][q] = w_hh2[(g * 3 + hs) * 3 + q];
            b2l[g] = b_ih2[g * 3 + hs] + b_hh2[g * 3 + hs];
        }
#pragma unroll
        for (int r = 0; r < 4; ++r) { h2p[r] = 0.f; c2[r] = 0.f; }
    }

    float creg[4] = {0.f, 0.f, 0.f, 0.f};

    // layer-2 elementwise (wave3, lanes 0-2 write): fully in-register via shfl
    auto L2EW = [&](int tout) {
        int hs = (l < 3) ? l : 0;
#pragma unroll
        for (int r = 0; r < 4; ++r) {
            float pi = __shfl(acc2[r], hs);
            float pf = __shfl(acc2[r], 3 + hs);
            float pg = __shfl(acc2[r], 6 + hs);
            float po = __shfl(acc2[r], 9 + hs);
            float hq0 = __shfl(h2p[r], 0);
            float hq1 = __shfl(h2p[r], 1);
            float hq2 = __shfl(h2p[r], 2);
            pi += b2l[0] + wh[0][0] * hq0 + wh[0][1] * hq1 + wh[0][2] * hq2;
            pf += b2l[1] + wh[1][0] * hq0 + wh[1][1] * hq1 + wh[1][2] * hq2;
            pg += b2l[2] + wh[2][0] * hq0 + wh[2][1] * hq1 + wh[2][2] * hq2;
            po += b2l[3] + wh[3][0] * hq0 + wh[3][1] * hq1 + wh[3][2] * hq2;
            float gi = sig2(pi), gf = sig2(pf), gg = tanh2(pg), go = sig2(po);
            c2[r] = gf * c2[r] + gi * gg;
            h2p[r] = go * tanh2(c2[r]);
            if (l < 3) out[(size_t)tout * 768 + (mw * 4 + r) * 3 + l] = h2p[r];
        }
    };

    // xg staging: every wave stages 1664 B/step (64 + 40 lanes of 16 B)
    const char* sp = (const char*)xg + (size_t)mw * XG_WG_BYTES + (size_t)wv * 1664;
    {
        char* d = (char*)xgs + wv * 1664;  // buf 0 (t=0)
        G2L16(sp + (size_t)l * 16, d);
        if (l < 40) G2L16(sp + 1024 + (size_t)l * 16, d + 1024);
        sp += XG_T_BYTES;
    }

    for (int t = 0; t < T_STEPS; ++t) {
        bf16x8 ha0 = LDHB(0), ha1 = LDHB(1), ha2 = LDHB(2);

        // stage xg(t+1): stays in flight across barrier (counted vmcnt)
        {
            char* d = (char*)xgs + ((t + 1) & 1) * 6656 + wv * 1664;
            G2L16(sp + (size_t)l * 16, d);
            if (l < 40) G2L16(sp + 1024 + (size_t)l * 16, d + 1024);
            sp += XG_T_BYTES;
        }
        if constexpr (L2O) {
            if (t >= 2) L2EW(t - 2);  // consumes prev-iteration acc2
        }

        f32x4 acc[CNT];
#pragma unroll
        for (int nt = 0; nt < CNT; ++nt)
            acc[nt] = __builtin_amdgcn_mfma_f32_16x16x32_bf16(ha0, wf[nt][0], fz, 0, 0, 0);
        if constexpr (L2O) acc2 = __builtin_amdgcn_mfma_f32_16x16x32_bf16(ha0, wf2[0], fz, 0, 0, 0);
        ha0 = LDHB(3);
#pragma unroll
        for (int nt = 0; nt < CNT; ++nt)
            acc[nt] = __builtin_amdgcn_mfma_f32_16x16x32_bf16(ha1, wf[nt][1], acc[nt], 0, 0, 0);
        if constexpr (L2O) acc2 = __builtin_amdgcn_mfma_f32_16x16x32_bf16(ha1, wf2[1], acc2, 0, 0, 0);
        ha1 = LDHB(4);
#pragma unroll
        for (int nt = 0; nt < CNT; ++nt)
            acc[nt] = __builtin_amdgcn_mfma_f32_16x16x32_bf16(ha2, wf[nt][2], acc[nt], 0, 0, 0);
        if constexpr (L2O) acc2 = __builtin_amdgcn_mfma_f32_16x16x32_bf16(ha2, wf2[2], acc2, 0, 0, 0);
        ha2 = LDHB(5);
#pragma unroll
        for (int nt = 0; nt < CNT; ++nt)
            acc[nt] = __builtin_amdgcn_mfma_f32_16x16x32_bf16(ha0, wf[nt][3], acc[nt], 0, 0, 0);
        if constexpr (L2O) acc2 = __builtin_amdgcn_mfma_f32_16x16x32_bf16(ha0, wf2[3], acc2, 0, 0, 0);
        ha0 = LDHB(6);
#pragma unroll
        for (int nt = 0; nt < CNT; ++nt)
            acc[nt] = __builtin_amdgcn_mfma_f32_16x16x32_bf16(ha1, wf[nt][4], acc[nt], 0, 0, 0);
        if constexpr (L2O) acc2 = __builtin_amdgcn_mfma_f32_16x16x32_bf16(ha1, wf2[4], acc2, 0, 0, 0);
#pragma unroll
        for (int nt = 0; nt < CNT; ++nt)
            acc[nt] = __builtin_amdgcn_mfma_f32_16x16x32_bf16(ha2, wf[nt][5], acc[nt], 0, 0, 0);
        if constexpr (L2O) acc2 = __builtin_amdgcn_mfma_f32_16x16x32_bf16(ha2, wf2[5], acc2, 0, 0, 0);
#pragma unroll
        for (int nt = 0; nt < CNT; ++nt)
            acc[nt] = __builtin_amdgcn_mfma_f32_16x16x32_bf16(ha0, wf[nt][6], acc[nt], 0, 0, 0);
        if constexpr (L2O) acc2 = __builtin_amdgcn_mfma_f32_16x16x32_bf16(ha0, wf2[6], acc2, 0, 0, 0);

        // gate stores: lanes<16, stride-1 cols, conflict-free
        if (l < 16) {
#pragma unroll
            for (int nt = 0; nt < CNT; ++nt) {
                int col = (tile0 + nt) * 16 + l;
#pragma unroll
                for (int r = 0; r < 4; ++r) gbuf[r * G1P + col] = acc[nt][r];
            }
        }

        asm volatile("s_waitcnt vmcnt(2)" ::: "memory");   // xg(t) ready; t+1 in flight
        asm volatile("s_waitcnt lgkmcnt(0)" ::: "memory");
        __builtin_amdgcn_s_barrier(); // b1

        // layer-1 elementwise: wave = batch row wv, j = r*64 + l
        {
            const float* gb = gbuf + wv * G1P;
            const u16* xr = xgs + (t & 1) * 3328 + wv * 832;
#pragma unroll
            for (int r = 0; r < 4; ++r) {
                int j = r * 64 + l;
                if (r < 3 || l < 8) {
                    float pi = gb[j] + bfu2f(xr[j]);
                    float pf = gb[H1 + j] + bfu2f(xr[H1 + j]);
                    float pg = gb[2 * H1 + j] + bfu2f(xr[2 * H1 + j]);
                    float po = gb[3 * H1 + j] + bfu2f(xr[3 * H1 + j]);
                    float gi = sig2(pi), gf = sig2(pf), gg = tanh2(pg), go = sig2(po);
                    float c = gf * creg[r] + gi * gg;
                    creg[r] = c;
                    float h = go * tanh2(c);
                    *(u16*)((char*)hbuf + ((wv * 448 + j * 2) ^ (wv << 4))) = f2bf(h);
                }
            }
        }

        asm volatile("s_waitcnt lgkmcnt(0)" ::: "memory");
        __builtin_amdgcn_s_barrier(); // b2
    }

    asm volatile("s_waitcnt vmcnt(0)" ::: "memory"); // drain dangling t=512 stage

    // epilogue (wave 3): finish layer-2 for steps 510 and 511
    if constexpr (L2O) {
        L2EW(510);
        bf16x8 he = LDHB(0);
        acc2 = __builtin_amdgcn_mfma_f32_16x16x32_bf16(he, wf2[0], fz, 0, 0, 0);
        he = LDHB(1); acc2 = __builtin_amdgcn_mfma_f32_16x16x32_bf16(he, wf2[1], acc2, 0, 0, 0);
        he = LDHB(2); acc2 = __builtin_amdgcn_mfma_f32_16x16x32_bf16(he, wf2[2], acc2, 0, 0, 0);
        he = LDHB(3); acc2 = __builtin_amdgcn_mfma_f32_16x16x32_bf16(he, wf2[3], acc2, 0, 0, 0);
        he = LDHB(4); acc2 = __builtin_amdgcn_mfma_f32_16x16x32_bf16(he, wf2[4], acc2, 0, 0, 0);
        he = LDHB(5); acc2 = __builtin_amdgcn_mfma_f32_16x16x32_bf16(he, wf2[5], acc2, 0, 0, 0);
        he = LDHB(6); acc2 = __builtin_amdgcn_mfma_f32_16x16x32_bf16(he, wf2[6], acc2, 0, 0, 0);
        L2EW(511);
    }
}

__global__ __launch_bounds__(256, 1) void lstm_main(const u16* __restrict__ xg,
                                                    const u16* __restrict__ whhf,
                                                    const float* __restrict__ w_ih2,
                                                    const float* __restrict__ w_hh2,
                                                    const float* __restrict__ b_ih2,
                                                    const float* __restrict__ b_hh2,
                                                    float* __restrict__ out) {
    __shared__ __align__(16) u16 hbuf[16 * KP];      // 7168 B, XOR-swizzled bf16 h
    __shared__ __align__(16) float gbuf[4 * G1P];    // 13312 B, gates [b][col]
    __shared__ __align__(16) u16 xgs[2 * 3328];      // 13312 B, staged xg (dbuf)

    int tid = threadIdx.x, mw = blockIdx.x;
    int l = tid & 63, wv = tid >> 6;

    for (int i = tid; i < 16 * KP; i += 256) hbuf[i] = 0;
    __syncthreads();

    if (wv == 0)
        lstm_body<13, false>(0, 0, l, mw, xg, whhf, w_ih2, w_hh2, b_ih2, b_hh2, out, hbuf, gbuf, xgs);
    else if (wv == 1)
        lstm_body<13, false>(13, 1, l, mw, xg, whhf, w_ih2, w_hh2, b_ih2, b_hh2, out, hbuf, gbuf, xgs);
    else if (wv == 2)
        lstm_body<12, false>(26, 2, l, mw, xg, whhf, w_ih2, w_hh2, b_ih2, b_hh2, out, hbuf, gbuf, xgs);
    else
        lstm_body<12, true>(38, 3, l, mw, xg, whhf, w_ih2, w_hh2, b_ih2, b_hh2, out, hbuf, gbuf, xgs);
}

extern "C" void kernel_launch(void* const* d_in, const int* in_sizes, int n_in,
                              void* d_out, int out_size, void* d_ws, size_t ws_size,
                              hipStream_t stream) {
    const float* X = (const float*)d_in[0];
    const float* w_ih1 = (const float*)d_in[1];
    const float* w_hh1 = (const float*)d_in[2];
    const float* b_ih1 = (const float*)d_in[3];
    const float* b_hh1 = (const float*)d_in[4];
    const float* w_ih2 = (const float*)d_in[5];
    const float* w_hh2 = (const float*)d_in[6];
    const float* b_ih2 = (const float*)d_in[7];
    const float* b_hh2 = (const float*)d_in[8];
    float* out = (float*)d_out;

    char* ws = (char*)d_ws;
    size_t off = 0;
    u16* xg = (u16*)(ws + off);
    off += (size_t)512 * 256 * G1P * 2; // 218,103,808 B (natural layout)
    u16* whhf = (u16*)(ws + off);
    off += (size_t)22400 * 8 * 2; // 358,400 B (also absorbs t=512 stage overread)
    u16* wihf = (u16*)(ws + off);
    off += (size_t)13312 * 8 * 2; // 212,992 B
    float* b1p = (float*)(ws + off);
    off += G1P * 4;
    if (ws_size < off) return; // insufficient workspace -> visible failure

    repack_k<<<140, 256, 0, stream>>>(w_ih1, w_hh1, b_ih1, b_hh1, wihf, whhf, b1p);
    xg_gemm<<<2048, 256, 0, stream>>>(X, wihf, b1p, xg);
    lstm_main<<<64, 256, 0, stream>>>(xg, whhf, w_ih2, w_hh2, b_ih2, b_hh2, out);
}

// Round 9
// 1205.357 us; speedup vs baseline: 1.6253x; 1.6253x over previous
//
#include <hip/hip_runtime.h>

typedef unsigned short u16;
typedef unsigned int u32;
typedef __attribute__((ext_vector_type(8))) short bf16x8;
typedef __attribute__((ext_vector_type(4))) float f32x4;

#define T_STEPS 512
#define FEAT 128
#define H1 200
#define G1 800
#define G1P 832
#define KP 224
#define XG_T_BYTES 425984   // 256 * 832 * 2
#define XG_WG_BYTES 6656    // 4 * 832 * 2

// async global->LDS, 16B/lane; LDS dest must be wave-uniform base (+lane*16 in HW)
#define G2L16(g, lp) __builtin_amdgcn_global_load_lds( \
    (const __attribute__((address_space(1))) void*)(g), \
    (__attribute__((address_space(3))) void*)(lp), 16, 0, 0)

__device__ __forceinline__ u16 f2bf(float x) {
    u32 u = __float_as_uint(x);
    u = (u + 0x7fffu + ((u >> 16) & 1u)) >> 16;
    return (u16)u;
}
__device__ __forceinline__ float bfu2f(u32 u) { return __uint_as_float(u << 16); }

__device__ __forceinline__ float sig2(float x) {
    return __builtin_amdgcn_rcpf(1.f + __builtin_amdgcn_exp2f(-1.442695041f * x));
}
__device__ __forceinline__ float tanh2(float x) {
    return 1.f - 2.f * __builtin_amdgcn_rcpf(1.f + __builtin_amdgcn_exp2f(2.885390082f * x));
}

// ---------------------------------------------------------------------------
// Kernel 1: repack weights to bf16 MFMA B-fragment order + fused bias.
// whhf: [tile*7+kt][lane][8], tile in [0,50); wihf: [ntg*4+kt][lane][8]
// (verbatim from round 4 — verified)
// ---------------------------------------------------------------------------
__global__ void repack_k(const float* __restrict__ wih1, const float* __restrict__ whh1,
                         const float* __restrict__ bih1, const float* __restrict__ bhh1,
                         u16* __restrict__ wihf, u16* __restrict__ whhf, float* __restrict__ b1p) {
    int id = blockIdx.x * 256 + threadIdx.x;
    if (id < G1P) b1p[id] = (id < G1) ? (bih1[id] + bhh1[id]) : 0.f;
    if (id < 22400) { // 50*7*64 lane-slots for whh
        int l = id & 63, fi = id >> 6;
        int kt = fi % 7, tile = fi / 7;
        int n = tile * 16 + (l & 15);
        int kb = kt * 32 + (l >> 4) * 8;
        u16 o[8];
#pragma unroll
        for (int j = 0; j < 8; ++j) {
            int k = kb + j;
            float v = (k < H1) ? whh1[n * H1 + k] : 0.f;
            o[j] = f2bf(v);
        }
        uint4 pk;
        pk.x = (u32)o[0] | ((u32)o[1] << 16);
        pk.y = (u32)o[2] | ((u32)o[3] << 16);
        pk.z = (u32)o[4] | ((u32)o[5] << 16);
        pk.w = (u32)o[6] | ((u32)o[7] << 16);
        *(uint4*)(whhf + (size_t)id * 8) = pk;
    }
    int id2 = id - 22400;
    if (id2 >= 0 && id2 < 13312) { // 52*4*64 lane-slots for wih
        int l = id2 & 63, fi = id2 >> 6;
        int kt = fi & 3, ntg = fi >> 2;
        int n = ntg * 16 + (l & 15);
        int kb = kt * 32 + (l >> 4) * 8;
        u16 o[8];
#pragma unroll
        for (int j = 0; j < 8; ++j) {
            int k = kb + j;
            float v = (n < G1) ? wih1[n * FEAT + k] : 0.f;
            o[j] = f2bf(v);
        }
        uint4 pk;
        pk.x = (u32)o[0] | ((u32)o[1] << 16);
        pk.y = (u32)o[2] | ((u32)o[3] << 16);
        pk.z = (u32)o[4] | ((u32)o[5] << 16);
        pk.w = (u32)o[6] | ((u32)o[7] << 16);
        *(uint4*)(wihf + (size_t)id2 * 8) = pk;
    }
}

// ---------------------------------------------------------------------------
// Kernel 2: xg = X @ W_ih1^T + bias, bf16, natural layout xg[t][b][col 0..831]
// (verbatim — verified)
// ---------------------------------------------------------------------------
__global__ __launch_bounds__(256, 1) void xg_gemm(const float* __restrict__ X,
                                                  const u16* __restrict__ wihf,
                                                  const float* __restrict__ b1p,
                                                  u16* __restrict__ xg) {
    __shared__ u16 xs[64 * 128];
    int tid = threadIdx.x, wg = blockIdx.x;
    int l = tid & 63, wv = tid >> 6;
    int arow = l & 15, khi = l >> 4;

    const float4* Xv = (const float4*)(X + (size_t)wg * 64 * 128);
#pragma unroll
    for (int i = 0; i < 8; ++i) {
        int idx = tid + i * 256;
        float4 v = Xv[idx];
        int row = idx >> 5;
        int col = (idx & 31) * 4;
        uint2 pk;
        pk.x = (u32)f2bf(v.x) | ((u32)f2bf(v.y) << 16);
        pk.y = (u32)f2bf(v.z) | ((u32)f2bf(v.w) << 16);
        int byteo = (row * 256 + col * 2) ^ ((row & 7) << 4);
        *(uint2*)((char*)xs + byteo) = pk;
    }
    __syncthreads();

    f32x4 acc[4][13];
#pragma unroll
    for (int mt = 0; mt < 4; ++mt)
#pragma unroll
        for (int nt = 0; nt < 13; ++nt) acc[mt][nt] = (f32x4){0.f, 0.f, 0.f, 0.f};

#pragma unroll
    for (int kt = 0; kt < 4; ++kt) {
        bf16x8 wfr[13];
#pragma unroll
        for (int nt = 0; nt < 13; ++nt) {
            int ntg = wv * 13 + nt;
            wfr[nt] = *(const bf16x8*)(wihf + ((size_t)(ntg * 4 + kt) * 64 + l) * 8);
        }
#pragma unroll
        for (int mt = 0; mt < 4; ++mt) {
            int row = mt * 16 + arow;
            int byteo = (row * 256 + kt * 64 + khi * 16) ^ ((row & 7) << 4);
            bf16x8 a = *(const bf16x8*)((const char*)xs + byteo);
#pragma unroll
            for (int nt = 0; nt < 13; ++nt)
                acc[mt][nt] = __builtin_amdgcn_mfma_f32_16x16x32_bf16(a, wfr[nt], acc[mt][nt], 0, 0, 0);
        }
    }

    int t = wg >> 2;
#pragma unroll
    for (int nt = 0; nt < 13; ++nt) {
        int ntg = wv * 13 + nt;
        int colg = ntg * 16 + arow;
        float bias = b1p[colg];
#pragma unroll
        for (int mt = 0; mt < 4; ++mt) {
#pragma unroll
            for (int r = 0; r < 4; ++r) {
                int bg = (wg & 3) * 64 + mt * 16 + khi * 4 + r;
                xg[((size_t)t * 256 + bg) * G1P + colg] = f2bf(acc[mt][nt][r] + bias);
            }
        }
    }
}

// ---------------------------------------------------------------------------
// Kernel 3: persistent fused 2-layer LSTM. 64 WGs x 512 threads (8 waves).
// amdgpu_waves_per_eu(2,2) -> 256-reg budget per wave, so 6 W_hh tiles/wave
// (168 regs) stay loop-resident WITHOUT remat (no asm pins — r5/7/8 lesson:
// the "+a" pin is implicated in every failure; plain compiler-managed regs
// passed every time). Tiles 47-49 from a 21.5 KB LDS copy (waves 0-2).
// All MFMA intrinsic. 2 barriers/step. Layer-2 on wave 7 (r4 verbatim).
// ---------------------------------------------------------------------------
#define LDHB(KT) (*(const bf16x8*)((const char*)hbuf + ((arow * 448 + (KT) * 64 + khi * 16) ^ ((arow & 7) << 4))))
#define LDSB(KT) (*(const bf16x8*)((const char*)wlds + (size_t)((LT * 7 + (KT)) * 1024) + l * 16))

template<int CNT, int MODE, int LT>  // MODE: 0 plain, 1 stager, 2 layer-2 owner; LT>=0: extra LDS tile
__device__ __forceinline__ void lstm_body(
    int tile0, int wv, int l, int mw,
    const u16* __restrict__ xg, const u16* __restrict__ whhf,
    const float* __restrict__ w_ih2, const float* __restrict__ w_hh2,
    const float* __restrict__ b_ih2, const float* __restrict__ b_hh2,
    float* __restrict__ out, u16* hbuf, float* gbuf, u16* xgs, const u16* wlds)
{
    constexpr bool HASL = (LT >= 0);
    const int arow = l & 15, khi = l >> 4;
    const int rw = wv >> 1, jbase = (wv & 1) * 100;
    const f32x4 fz = {0.f, 0.f, 0.f, 0.f};

    // persistent W_hh B-fragments — plain loads, compiler-managed registers
    bf16x8 wf[CNT][7];
#pragma unroll
    for (int nt = 0; nt < CNT; ++nt)
#pragma unroll
        for (int kt = 0; kt < 7; ++kt)
            wf[nt][kt] = *(const bf16x8*)(whhf + ((size_t)((tile0 + nt) * 7 + kt) * 64 + l) * 8);

    // layer-2 state (wave 7 only; DCE'd elsewhere) — r4 verbatim
    bf16x8 wf2[7];
    float wh[4][3], b2l[4], h2p[4], c2[4];
    f32x4 acc2 = fz;
    if constexpr (MODE == 2) {
#pragma unroll
        for (int kt = 0; kt < 7; ++kt) {
            u16 o[8];
#pragma unroll
            for (int j = 0; j < 8; ++j) {
                int k = kt * 32 + khi * 8 + j;
                o[j] = (arow < 12 && k < H1) ? f2bf(w_ih2[arow * H1 + k]) : (u16)0;
            }
            uint4 pk;
            pk.x = (u32)o[0] | ((u32)o[1] << 16);
            pk.y = (u32)o[2] | ((u32)o[3] << 16);
            pk.z = (u32)o[4] | ((u32)o[5] << 16);
            pk.w = (u32)o[6] | ((u32)o[7] << 16);
            wf2[kt] = *(bf16x8*)&pk;
        }
        int hs = (l < 3) ? l : 0;
#pragma unroll
        for (int g = 0; g < 4; ++g) {
#pragma unroll
            for (int q = 0; q < 3; ++q) wh[g][q] = w_hh2[(g * 3 + hs) * 3 + q];
            b2l[g] = b_ih2[g * 3 + hs] + b_hh2[g * 3 + hs];
        }
#pragma unroll
        for (int r = 0; r < 4; ++r) { h2p[r] = 0.f; c2[r] = 0.f; }
    }

    float creg0 = 0.f, creg1 = 0.f;

    auto L2EW = [&](int tout) {
        int hs = (l < 3) ? l : 0;
#pragma unroll
        for (int r = 0; r < 4; ++r) {
            float pi = __shfl(acc2[r], hs);
            float pf = __shfl(acc2[r], 3 + hs);
            float pg = __shfl(acc2[r], 6 + hs);
            float po = __shfl(acc2[r], 9 + hs);
            float hq0 = __shfl(h2p[r], 0);
            float hq1 = __shfl(h2p[r], 1);
            float hq2 = __shfl(h2p[r], 2);
            pi += b2l[0] + wh[0][0] * hq0 + wh[0][1] * hq1 + wh[0][2] * hq2;
            pf += b2l[1] + wh[1][0] * hq0 + wh[1][1] * hq1 + wh[1][2] * hq2;
            pg += b2l[2] + wh[2][0] * hq0 + wh[2][1] * hq1 + wh[2][2] * hq2;
            po += b2l[3] + wh[3][0] * hq0 + wh[3][1] * hq1 + wh[3][2] * hq2;
            float gi = sig2(pi), gf = sig2(pf), gg = tanh2(pg), go = sig2(po);
            c2[r] = gf * c2[r] + gi * gg;
            h2p[r] = go * tanh2(c2[r]);
            if (l < 3) out[(size_t)tout * 768 + (mw * 4 + r) * 3 + l] = h2p[r];
        }
    };

    // xg staging: waves 3-6, 1664 B/step each (64 + 40 lanes of 16 B) — r4 verbatim
    const char* sp = (const char*)xg + (size_t)mw * XG_WG_BYTES + (size_t)(wv - 3) * 1664;
    if constexpr (MODE == 1) {
        char* d = (char*)xgs + (wv - 3) * 1664;  // buf 0 (t=0)
        G2L16(sp + (size_t)l * 16, d);
        if (l < 40) G2L16(sp + 1024 + (size_t)l * 16, d + 1024);
        sp += XG_T_BYTES;
    }

    for (int t = 0; t < T_STEPS; ++t) {
        bf16x8 ha0 = LDHB(0), ha1 = LDHB(1), ha2 = LDHB(2);
        bf16x8 wb0, wb1;
        if constexpr (HASL) wb0 = LDSB(0);

        if constexpr (MODE == 1) {
            char* d = (char*)xgs + ((t + 1) & 1) * 6656 + (wv - 3) * 1664;
            G2L16(sp + (size_t)l * 16, d);
            if (l < 40) G2L16(sp + 1024 + (size_t)l * 16, d + 1024);
            sp += XG_T_BYTES;
        }
        if constexpr (MODE == 2) {
            if (t >= 2) L2EW(t - 2);  // consumes prev-iteration acc2
        }

        f32x4 acc[CNT], aL;
        // kt = 0
#pragma unroll
        for (int nt = 0; nt < CNT; ++nt)
            acc[nt] = __builtin_amdgcn_mfma_f32_16x16x32_bf16(ha0, wf[nt][0], fz, 0, 0, 0);
        if constexpr (HASL) { aL = __builtin_amdgcn_mfma_f32_16x16x32_bf16(ha0, wb0, fz, 0, 0, 0); wb1 = LDSB(1); }
        if constexpr (MODE == 2) acc2 = __builtin_amdgcn_mfma_f32_16x16x32_bf16(ha0, wf2[0], fz, 0, 0, 0);
        ha0 = LDHB(3);
        // kt = 1
#pragma unroll
        for (int nt = 0; nt < CNT; ++nt)
            acc[nt] = __builtin_amdgcn_mfma_f32_16x16x32_bf16(ha1, wf[nt][1], acc[nt], 0, 0, 0);
        if constexpr (HASL) { aL = __builtin_amdgcn_mfma_f32_16x16x32_bf16(ha1, wb1, aL, 0, 0, 0); wb0 = LDSB(2); }
        if constexpr (MODE == 2) acc2 = __builtin_amdgcn_mfma_f32_16x16x32_bf16(ha1, wf2[1], acc2, 0, 0, 0);
        ha1 = LDHB(4);
        // kt = 2
#pragma unroll
        for (int nt = 0; nt < CNT; ++nt)
            acc[nt] = __builtin_amdgcn_mfma_f32_16x16x32_bf16(ha2, wf[nt][2], acc[nt], 0, 0, 0);
        if constexpr (HASL) { aL = __builtin_amdgcn_mfma_f32_16x16x32_bf16(ha2, wb0, aL, 0, 0, 0); wb1 = LDSB(3); }
        if constexpr (MODE == 2) acc2 = __builtin_amdgcn_mfma_f32_16x16x32_bf16(ha2, wf2[2], acc2, 0, 0, 0);
        ha2 = LDHB(5);
        // kt = 3
#pragma unroll
        for (int nt = 0; nt < CNT; ++nt)
            acc[nt] = __builtin_amdgcn_mfma_f32_16x16x32_bf16(ha0, wf[nt][3], acc[nt], 0, 0, 0);
        if constexpr (HASL) { aL = __builtin_amdgcn_mfma_f32_16x16x32_bf16(ha0, wb1, aL, 0, 0, 0); wb0 = LDSB(4); }
        if constexpr (MODE == 2) acc2 = __builtin_amdgcn_mfma_f32_16x16x32_bf16(ha0, wf2[3], acc2, 0, 0, 0);
        ha0 = LDHB(6);
        // kt = 4
#pragma unroll
        for (int nt = 0; nt < CNT; ++nt)
            acc[nt] = __builtin_amdgcn_mfma_f32_16x16x32_bf16(ha1, wf[nt][4], acc[nt], 0, 0, 0);
        if constexpr (HASL) { aL = __builtin_amdgcn_mfma_f32_16x16x32_bf16(ha1, wb0, aL, 0, 0, 0); wb1 = LDSB(5); }
        if constexpr (MODE == 2) acc2 = __builtin_amdgcn_mfma_f32_16x16x32_bf16(ha1, wf2[4], acc2, 0, 0, 0);
        // kt = 5
#pragma unroll
        for (int nt = 0; nt < CNT; ++nt)
            acc[nt] = __builtin_amdgcn_mfma_f32_16x16x32_bf16(ha2, wf[nt][5], acc[nt], 0, 0, 0);
        if constexpr (HASL) { aL = __builtin_amdgcn_mfma_f32_16x16x32_bf16(ha2, wb1, aL, 0, 0, 0); wb0 = LDSB(6); }
        if constexpr (MODE == 2) acc2 = __builtin_amdgcn_mfma_f32_16x16x32_bf16(ha2, wf2[5], acc2, 0, 0, 0);
        // kt = 6
#pragma unroll
        for (int nt = 0; nt < CNT; ++nt)
            acc[nt] = __builtin_amdgcn_mfma_f32_16x16x32_bf16(ha0, wf[nt][6], acc[nt], 0, 0, 0);
        if constexpr (HASL) aL = __builtin_amdgcn_mfma_f32_16x16x32_bf16(ha0, wb0, aL, 0, 0, 0);
        if constexpr (MODE == 2) acc2 = __builtin_amdgcn_mfma_f32_16x16x32_bf16(ha0, wf2[6], acc2, 0, 0, 0);

        // gate stores: lanes<16, stride-1 cols, conflict-free
        if (l < 16) {
#pragma unroll
            for (int nt = 0; nt < CNT; ++nt) {
                int col = (tile0 + nt) * 16 + l;
#pragma unroll
                for (int r = 0; r < 4; ++r) gbuf[r * G1P + col] = acc[nt][r];
            }
            if constexpr (HASL) {
                int col = (47 + LT) * 16 + l;
#pragma unroll
                for (int r = 0; r < 4; ++r) gbuf[r * G1P + col] = aL[r];
            }
        }

        if constexpr (MODE == 1) asm volatile("s_waitcnt vmcnt(2)" ::: "memory");
        asm volatile("s_waitcnt lgkmcnt(0)" ::: "memory");
        __builtin_amdgcn_s_barrier(); // b1

        // layer-1 elementwise: wave -> (row rw, cols jbase..jbase+100) — r4 verbatim
        {
            const float* gb = gbuf + rw * G1P + jbase;
            const u16* xr = xgs + (t & 1) * 3328 + rw * G1P + jbase;
            float p0[4], p1[4];
#pragma unroll
            for (int g = 0; g < 4; ++g) p0[g] = gb[g * 200 + l] + bfu2f(xr[g * 200 + l]);
#pragma unroll
            for (int g = 0; g < 4; ++g) p1[g] = gb[g * 200 + 64 + l] + bfu2f(xr[g * 200 + 64 + l]);
            {
                float gi = sig2(p0[0]), gf = sig2(p0[1]), gg = tanh2(p0[2]), go = sig2(p0[3]);
                creg0 = gf * creg0 + gi * gg;
                float h = go * tanh2(creg0);
                *(u16*)((char*)hbuf + ((rw * 448 + (jbase + l) * 2) ^ ((rw & 7) << 4))) = f2bf(h);
            }
            if (l < 36) {
                float gi = sig2(p1[0]), gf = sig2(p1[1]), gg = tanh2(p1[2]), go = sig2(p1[3]);
                creg1 = gf * creg1 + gi * gg;
                float h = go * tanh2(creg1);
                *(u16*)((char*)hbuf + ((rw * 448 + (jbase + 64 + l) * 2) ^ ((rw & 7) << 4))) = f2bf(h);
            }
        }

        asm volatile("s_waitcnt lgkmcnt(0)" ::: "memory");
        __builtin_amdgcn_s_barrier(); // b2
    }

    asm volatile("s_waitcnt vmcnt(0)" ::: "memory"); // drain dangling t=512 stage

    // epilogue (wave 7): layer-2 for steps 510 and 511 — r4 verbatim
    if constexpr (MODE == 2) {
        L2EW(510);
        bf16x8 he = LDHB(0);
        acc2 = __builtin_amdgcn_mfma_f32_16x16x32_bf16(he, wf2[0], fz, 0, 0, 0);
        he = LDHB(1); acc2 = __builtin_amdgcn_mfma_f32_16x16x32_bf16(he, wf2[1], acc2, 0, 0, 0);
        he = LDHB(2); acc2 = __builtin_amdgcn_mfma_f32_16x16x32_bf16(he, wf2[2], acc2, 0, 0, 0);
        he = LDHB(3); acc2 = __builtin_amdgcn_mfma_f32_16x16x32_bf16(he, wf2[3], acc2, 0, 0, 0);
        he = LDHB(4); acc2 = __builtin_amdgcn_mfma_f32_16x16x32_bf16(he, wf2[4], acc2, 0, 0, 0);
        he = LDHB(5); acc2 = __builtin_amdgcn_mfma_f32_16x16x32_bf16(he, wf2[5], acc2, 0, 0, 0);
        he = LDHB(6); acc2 = __builtin_amdgcn_mfma_f32_16x16x32_bf16(he, wf2[6], acc2, 0, 0, 0);
        L2EW(511);
    }
}

__global__ __launch_bounds__(512) __attribute__((amdgpu_waves_per_eu(2, 2)))
void lstm_main(const u16* __restrict__ xg,
               const u16* __restrict__ whhf,
               const float* __restrict__ w_ih2,
               const float* __restrict__ w_hh2,
               const float* __restrict__ b_ih2,
               const float* __restrict__ b_hh2,
               float* __restrict__ out) {
    __shared__ __align__(16) u16 hbuf[16 * KP];      //  7168 B, XOR-swizzled bf16 h
    __shared__ __align__(16) float gbuf[4 * G1P];    // 13312 B, gates [b][col]
    __shared__ __align__(16) u16 xgs[2 * 3328];      // 13312 B, staged xg (dbuf)
    __shared__ __align__(16) u16 wlds[3 * 7 * 512];  // 21504 B, B-frags: tiles 47-49

    int tid = threadIdx.x, mw = blockIdx.x;
    int l = tid & 63, wv = tid >> 6;

    for (int i = tid; i < 16 * KP; i += 512) hbuf[i] = 0;
    // copy tiles 47..49 B-fragments into LDS (contiguous in whhf)
    {
        const uint4* src = (const uint4*)(whhf + (size_t)(47 * 7) * 512);
        uint4* dst = (uint4*)wlds;
        for (int i = tid; i < 1344; i += 512) dst[i] = src[i];
    }
    __syncthreads();

    // reg tiles: w0-w6 = 6 each (0-41), w7 = 5 (42-46); LDS tiles 47-49 on w0-w2
    if (wv == 0)
        lstm_body<6, 0, 0>(0, 0, l, mw, xg, whhf, w_ih2, w_hh2, b_ih2, b_hh2, out, hbuf, gbuf, xgs, wlds);
    else if (wv == 1)
        lstm_body<6, 0, 1>(6, 1, l, mw, xg, whhf, w_ih2, w_hh2, b_ih2, b_hh2, out, hbuf, gbuf, xgs, wlds);
    else if (wv == 2)
        lstm_body<6, 0, 2>(12, 2, l, mw, xg, whhf, w_ih2, w_hh2, b_ih2, b_hh2, out, hbuf, gbuf, xgs, wlds);
    else if (wv < 7)
        lstm_body<6, 1, -1>(18 + (wv - 3) * 6, wv, l, mw, xg, whhf, w_ih2, w_hh2, b_ih2, b_hh2, out, hbuf, gbuf, xgs, wlds);
    else
        lstm_body<5, 2, -1>(42, 7, l, mw, xg, whhf, w_ih2, w_hh2, b_ih2, b_hh2, out, hbuf, gbuf, xgs, wlds);
}

extern "C" void kernel_launch(void* const* d_in, const int* in_sizes, int n_in,
                              void* d_out, int out_size, void* d_ws, size_t ws_size,
                              hipStream_t stream) {
    const float* X = (const float*)d_in[0];
    const float* w_ih1 = (const float*)d_in[1];
    const float* w_hh1 = (const float*)d_in[2];
    const float* b_ih1 = (const float*)d_in[3];
    const float* b_hh1 = (const float*)d_in[4];
    const float* w_ih2 = (const float*)d_in[5];
    const float* w_hh2 = (const float*)d_in[6];
    const float* b_ih2 = (const float*)d_in[7];
    const float* b_hh2 = (const float*)d_in[8];
    float* out = (float*)d_out;

    char* ws = (char*)d_ws;
    size_t off = 0;
    u16* xg = (u16*)(ws + off);
    off += (size_t)512 * 256 * G1P * 2; // 218,103,808 B (natural layout)
    u16* whhf = (u16*)(ws + off);
    off += (size_t)22400 * 8 * 2; // 358,400 B (also absorbs t=512 stage overread)
    u16* wihf = (u16*)(ws + off);
    off += (size_t)13312 * 8 * 2; // 212,992 B
    float* b1p = (float*)(ws + off);
    off += G1P * 4;
    if (ws_size < off) return; // insufficient workspace -> visible failure

    repack_k<<<140, 256, 0, stream>>>(w_ih1, w_hh1, b_ih1, b_hh1, wihf, whhf, b1p);
    xg_gemm<<<2048, 256, 0, stream>>>(X, wihf, b1p, xg);
    lstm_main<<<64, 512, 0, stream>>>(xg, whhf, w_ih2, w_hh2, b_ih2, b_hh2, out);
}

// Round 10
// 1028.137 us; speedup vs baseline: 1.9054x; 1.1724x over previous
//
#include <hip/hip_runtime.h>

typedef unsigned short u16;
typedef unsigned int u32;
typedef __attribute__((ext_vector_type(8))) short bf16x8;
typedef __attribute__((ext_vector_type(4))) float f32x4;

#define T_STEPS 512
#define FEAT 128
#define H1 200
#define G1 800
#define G1P 832
#define KP 224
#define XG_T_BYTES 425984   // 256 * 832 * 2
#define XG_WG_BYTES 6656    // 4 * 832 * 2

// async global->LDS, 16B/lane; LDS dest must be wave-uniform base (+lane*16 in HW)
#define G2L16(g, lp) __builtin_amdgcn_global_load_lds( \
    (const __attribute__((address_space(1))) void*)(g), \
    (__attribute__((address_space(3))) void*)(lp), 16, 0, 0)

__device__ __forceinline__ u16 f2bf(float x) {
    u32 u = __float_as_uint(x);
    u = (u + 0x7fffu + ((u >> 16) & 1u)) >> 16;
    return (u16)u;
}
__device__ __forceinline__ float bfu2f(u32 u) { return __uint_as_float(u << 16); }

__device__ __forceinline__ float sig2(float x) {
    return __builtin_amdgcn_rcpf(1.f + __builtin_amdgcn_exp2f(-1.442695041f * x));
}
__device__ __forceinline__ float tanh2(float x) {
    return 1.f - 2.f * __builtin_amdgcn_rcpf(1.f + __builtin_amdgcn_exp2f(2.885390082f * x));
}

// ---------------------------------------------------------------------------
// Kernel 1: repack weights to bf16 MFMA B-fragment order + fused bias.
// whhf: [tile*7+kt][lane][8], tile in [0,50); wihf: [ntg*4+kt][lane][8]
// (verbatim — verified)
// ---------------------------------------------------------------------------
__global__ void repack_k(const float* __restrict__ wih1, const float* __restrict__ whh1,
                         const float* __restrict__ bih1, const float* __restrict__ bhh1,
                         u16* __restrict__ wihf, u16* __restrict__ whhf, float* __restrict__ b1p) {
    int id = blockIdx.x * 256 + threadIdx.x;
    if (id < G1P) b1p[id] = (id < G1) ? (bih1[id] + bhh1[id]) : 0.f;
    if (id < 22400) { // 50*7*64 lane-slots for whh
        int l = id & 63, fi = id >> 6;
        int kt = fi % 7, tile = fi / 7;
        int n = tile * 16 + (l & 15);
        int kb = kt * 32 + (l >> 4) * 8;
        u16 o[8];
#pragma unroll
        for (int j = 0; j < 8; ++j) {
            int k = kb + j;
            float v = (k < H1) ? whh1[n * H1 + k] : 0.f;
            o[j] = f2bf(v);
        }
        uint4 pk;
        pk.x = (u32)o[0] | ((u32)o[1] << 16);
        pk.y = (u32)o[2] | ((u32)o[3] << 16);
        pk.z = (u32)o[4] | ((u32)o[5] << 16);
        pk.w = (u32)o[6] | ((u32)o[7] << 16);
        *(uint4*)(whhf + (size_t)id * 8) = pk;
    }
    int id2 = id - 22400;
    if (id2 >= 0 && id2 < 13312) { // 52*4*64 lane-slots for wih
        int l = id2 & 63, fi = id2 >> 6;
        int kt = fi & 3, ntg = fi >> 2;
        int n = ntg * 16 + (l & 15);
        int kb = kt * 32 + (l >> 4) * 8;
        u16 o[8];
#pragma unroll
        for (int j = 0; j < 8; ++j) {
            int k = kb + j;
            float v = (n < G1) ? wih1[n * FEAT + k] : 0.f;
            o[j] = f2bf(v);
        }
        uint4 pk;
        pk.x = (u32)o[0] | ((u32)o[1] << 16);
        pk.y = (u32)o[2] | ((u32)o[3] << 16);
        pk.z = (u32)o[4] | ((u32)o[5] << 16);
        pk.w = (u32)o[6] | ((u32)o[7] << 16);
        *(uint4*)(wihf + (size_t)id2 * 8) = pk;
    }
}

// ---------------------------------------------------------------------------
// Kernel 2: xg = X @ W_ih1^T + bias, bf16, natural layout xg[t][b][col 0..831]
// (verbatim — verified)
// ---------------------------------------------------------------------------
__global__ __launch_bounds__(256, 1) void xg_gemm(const float* __restrict__ X,
                                                  const u16* __restrict__ wihf,
                                                  const float* __restrict__ b1p,
                                                  u16* __restrict__ xg) {
    __shared__ u16 xs[64 * 128];
    int tid = threadIdx.x, wg = blockIdx.x;
    int l = tid & 63, wv = tid >> 6;
    int arow = l & 15, khi = l >> 4;

    const float4* Xv = (const float4*)(X + (size_t)wg * 64 * 128);
#pragma unroll
    for (int i = 0; i < 8; ++i) {
        int idx = tid + i * 256;
        float4 v = Xv[idx];
        int row = idx >> 5;
        int col = (idx & 31) * 4;
        uint2 pk;
        pk.x = (u32)f2bf(v.x) | ((u32)f2bf(v.y) << 16);
        pk.y = (u32)f2bf(v.z) | ((u32)f2bf(v.w) << 16);
        int byteo = (row * 256 + col * 2) ^ ((row & 7) << 4);
        *(uint2*)((char*)xs + byteo) = pk;
    }
    __syncthreads();

    f32x4 acc[4][13];
#pragma unroll
    for (int mt = 0; mt < 4; ++mt)
#pragma unroll
        for (int nt = 0; nt < 13; ++nt) acc[mt][nt] = (f32x4){0.f, 0.f, 0.f, 0.f};

#pragma unroll
    for (int kt = 0; kt < 4; ++kt) {
        bf16x8 wfr[13];
#pragma unroll
        for (int nt = 0; nt < 13; ++nt) {
            int ntg = wv * 13 + nt;
            wfr[nt] = *(const bf16x8*)(wihf + ((size_t)(ntg * 4 + kt) * 64 + l) * 8);
        }
#pragma unroll
        for (int mt = 0; mt < 4; ++mt) {
            int row = mt * 16 + arow;
            int byteo = (row * 256 + kt * 64 + khi * 16) ^ ((row & 7) << 4);
            bf16x8 a = *(const bf16x8*)((const char*)xs + byteo);
#pragma unroll
            for (int nt = 0; nt < 13; ++nt)
                acc[mt][nt] = __builtin_amdgcn_mfma_f32_16x16x32_bf16(a, wfr[nt], acc[mt][nt], 0, 0, 0);
        }
    }

    int t = wg >> 2;
#pragma unroll
    for (int nt = 0; nt < 13; ++nt) {
        int ntg = wv * 13 + nt;
        int colg = ntg * 16 + arow;
        float bias = b1p[colg];
#pragma unroll
        for (int mt = 0; mt < 4; ++mt) {
#pragma unroll
            for (int r = 0; r < 4; ++r) {
                int bg = (wg & 3) * 64 + mt * 16 + khi * 4 + r;
                xg[((size_t)t * 256 + bg) * G1P + colg] = f2bf(acc[mt][nt][r] + bias);
            }
        }
    }
}

// ---------------------------------------------------------------------------
// Kernel 3: persistent fused 2-layer LSTM. 64 WGs x 512 threads (8 waves).
// LDS = 110 KB -> 1 WG/CU -> compiler occupancy ceiling 2 waves/SIMD ->
// 256-reg budget per wave. Per wave: 5 W_hh tiles in VGPRs (140 regs, ~215
// peak, comfortable slack); 11 tiles served from LDS (ds_read_b128, lane*16
// conflict-free layout, double-buffered over kt). All MFMA intrinsic, no asm
// pins. Waves 3-6 stage xg; wave 7 owns layer-2 in-register. 2 barriers/step.
// ---------------------------------------------------------------------------
#define LDHB(KT) (*(const bf16x8*)((const char*)hbuf + ((arow * 448 + (KT) * 64 + khi * 16) ^ ((arow & 7) << 4))))
#define LDSW(J, KT) (*(const bf16x8*)((const char*)wldsw + (size_t)(((J) * 7 + (KT)) * 1024) + l * 16))

template<int CNT, int NL, int MODE>  // MODE: 0 plain, 1 stager, 2 layer-2 owner
__device__ __forceinline__ void lstm_body(
    int tile0, int ls0, int wv, int l, int mw,
    const u16* __restrict__ xg, const u16* __restrict__ whhf,
    const float* __restrict__ w_ih2, const float* __restrict__ w_hh2,
    const float* __restrict__ b_ih2, const float* __restrict__ b_hh2,
    float* __restrict__ out, u16* hbuf, float* gbuf, u16* xgs, const u16* wlds)
{
    const int arow = l & 15, khi = l >> 4;
    const int rw = wv >> 1, jbase = (wv & 1) * 100;
    const f32x4 fz = {0.f, 0.f, 0.f, 0.f};
    const u16* wldsw = wlds + (size_t)ls0 * 7 * 512;  // this wave's LDS tile base

    // persistent W_hh B-fragments — plain loads, compiler-managed VGPRs
    bf16x8 wf[CNT][7];
#pragma unroll
    for (int nt = 0; nt < CNT; ++nt)
#pragma unroll
        for (int kt = 0; kt < 7; ++kt)
            wf[nt][kt] = *(const bf16x8*)(whhf + ((size_t)((tile0 + nt) * 7 + kt) * 64 + l) * 8);

    // layer-2 state (wave 7 only; DCE'd elsewhere) — r9 verbatim
    bf16x8 wf2[7];
    float wh[4][3], b2l[4], h2p[4], c2[4];
    f32x4 acc2 = fz;
    if constexpr (MODE == 2) {
#pragma unroll
        for (int kt = 0; kt < 7; ++kt) {
            u16 o[8];
#pragma unroll
            for (int j = 0; j < 8; ++j) {
                int k = kt * 32 + khi * 8 + j;
                o[j] = (arow < 12 && k < H1) ? f2bf(w_ih2[arow * H1 + k]) : (u16)0;
            }
            uint4 pk;
            pk.x = (u32)o[0] | ((u32)o[1] << 16);
            pk.y = (u32)o[2] | ((u32)o[3] << 16);
            pk.z = (u32)o[4] | ((u32)o[5] << 16);
            pk.w = (u32)o[6] | ((u32)o[7] << 16);
            wf2[kt] = *(bf16x8*)&pk;
        }
        int hs = (l < 3) ? l : 0;
#pragma unroll
        for (int g = 0; g < 4; ++g) {
#pragma unroll
            for (int q = 0; q < 3; ++q) wh[g][q] = w_hh2[(g * 3 + hs) * 3 + q];
            b2l[g] = b_ih2[g * 3 + hs] + b_hh2[g * 3 + hs];
        }
#pragma unroll
        for (int r = 0; r < 4; ++r) { h2p[r] = 0.f; c2[r] = 0.f; }
    }

    float creg0 = 0.f, creg1 = 0.f;

    auto L2EW = [&](int tout) {
        int hs = (l < 3) ? l : 0;
#pragma unroll
        for (int r = 0; r < 4; ++r) {
            float pi = __shfl(acc2[r], hs);
            float pf = __shfl(acc2[r], 3 + hs);
            float pg = __shfl(acc2[r], 6 + hs);
            float po = __shfl(acc2[r], 9 + hs);
            float hq0 = __shfl(h2p[r], 0);
            float hq1 = __shfl(h2p[r], 1);
            float hq2 = __shfl(h2p[r], 2);
            pi += b2l[0] + wh[0][0] * hq0 + wh[0][1] * hq1 + wh[0][2] * hq2;
            pf += b2l[1] + wh[1][0] * hq0 + wh[1][1] * hq1 + wh[1][2] * hq2;
            pg += b2l[2] + wh[2][0] * hq0 + wh[2][1] * hq1 + wh[2][2] * hq2;
            po += b2l[3] + wh[3][0] * hq0 + wh[3][1] * hq1 + wh[3][2] * hq2;
            float gi = sig2(pi), gf = sig2(pf), gg = tanh2(pg), go = sig2(po);
            c2[r] = gf * c2[r] + gi * gg;
            h2p[r] = go * tanh2(c2[r]);
            if (l < 3) out[(size_t)tout * 768 + (mw * 4 + r) * 3 + l] = h2p[r];
        }
    };

    // xg staging: waves 3-6, 1664 B/step each (64 + 40 lanes of 16 B) — verified
    const char* sp = (const char*)xg + (size_t)mw * XG_WG_BYTES + (size_t)(wv - 3) * 1664;
    if constexpr (MODE == 1) {
        char* d = (char*)xgs + (wv - 3) * 1664;  // buf 0 (t=0)
        G2L16(sp + (size_t)l * 16, d);
        if (l < 40) G2L16(sp + 1024 + (size_t)l * 16, d + 1024);
        sp += XG_T_BYTES;
    }

    for (int t = 0; t < T_STEPS; ++t) {
        bf16x8 ha0 = LDHB(0), ha1 = LDHB(1), ha2 = LDHB(2);
        bf16x8 wb[NL ? NL : 1][2];
        if constexpr (NL > 0) {
#pragma unroll
            for (int j = 0; j < NL; ++j) wb[j][0] = LDSW(j, 0);
        }

        if constexpr (MODE == 1) {
            char* d = (char*)xgs + ((t + 1) & 1) * 6656 + (wv - 3) * 1664;
            G2L16(sp + (size_t)l * 16, d);
            if (l < 40) G2L16(sp + 1024 + (size_t)l * 16, d + 1024);
            sp += XG_T_BYTES;
        }
        if constexpr (MODE == 2) {
            if (t >= 2) L2EW(t - 2);  // consumes prev-iteration acc2
        }

        f32x4 acc[CNT], accL[NL ? NL : 1];
        // kt = 0
        if constexpr (NL > 0) {
#pragma unroll
            for (int j = 0; j < NL; ++j) wb[j][1] = LDSW(j, 1);
        }
#pragma unroll
        for (int nt = 0; nt < CNT; ++nt)
            acc[nt] = __builtin_amdgcn_mfma_f32_16x16x32_bf16(ha0, wf[nt][0], fz, 0, 0, 0);
        if constexpr (NL > 0) {
#pragma unroll
            for (int j = 0; j < NL; ++j)
                accL[j] = __builtin_amdgcn_mfma_f32_16x16x32_bf16(ha0, wb[j][0], fz, 0, 0, 0);
        }
        if constexpr (MODE == 2) acc2 = __builtin_amdgcn_mfma_f32_16x16x32_bf16(ha0, wf2[0], fz, 0, 0, 0);
        ha0 = LDHB(3);
        // kt = 1
        if constexpr (NL > 0) {
#pragma unroll
            for (int j = 0; j < NL; ++j) wb[j][0] = LDSW(j, 2);
        }
#pragma unroll
        for (int nt = 0; nt < CNT; ++nt)
            acc[nt] = __builtin_amdgcn_mfma_f32_16x16x32_bf16(ha1, wf[nt][1], acc[nt], 0, 0, 0);
        if constexpr (NL > 0) {
#pragma unroll
            for (int j = 0; j < NL; ++j)
                accL[j] = __builtin_amdgcn_mfma_f32_16x16x32_bf16(ha1, wb[j][1], accL[j], 0, 0, 0);
        }
        if constexpr (MODE == 2) acc2 = __builtin_amdgcn_mfma_f32_16x16x32_bf16(ha1, wf2[1], acc2, 0, 0, 0);
        ha1 = LDHB(4);
        // kt = 2
        if constexpr (NL > 0) {
#pragma unroll
            for (int j = 0; j < NL; ++j) wb[j][1] = LDSW(j, 3);
        }
#pragma unroll
        for (int nt = 0; nt < CNT; ++nt)
            acc[nt] = __builtin_amdgcn_mfma_f32_16x16x32_bf16(ha2, wf[nt][2], acc[nt], 0, 0, 0);
        if constexpr (NL > 0) {
#pragma unroll
            for (int j = 0; j < NL; ++j)
                accL[j] = __builtin_amdgcn_mfma_f32_16x16x32_bf16(ha2, wb[j][0], accL[j], 0, 0, 0);
        }
        if constexpr (MODE == 2) acc2 = __builtin_amdgcn_mfma_f32_16x16x32_bf16(ha2, wf2[2], acc2, 0, 0, 0);
        ha2 = LDHB(5);
        // kt = 3
        if constexpr (NL > 0) {
#pragma unroll
            for (int j = 0; j < NL; ++j) wb[j][0] = LDSW(j, 4);
        }
#pragma unroll
        for (int nt = 0; nt < CNT; ++nt)
            acc[nt] = __builtin_amdgcn_mfma_f32_16x16x32_bf16(ha0, wf[nt][3], acc[nt], 0, 0, 0);
        if constexpr (NL > 0) {
#pragma unroll
            for (int j = 0; j < NL; ++j)
                accL[j] = __builtin_amdgcn_mfma_f32_16x16x32_bf16(ha0, wb[j][1], accL[j], 0, 0, 0);
        }
        if constexpr (MODE == 2) acc2 = __builtin_amdgcn_mfma_f32_16x16x32_bf16(ha0, wf2[3], acc2, 0, 0, 0);
        ha0 = LDHB(6);
        // kt = 4
        if constexpr (NL > 0) {
#pragma unroll
            for (int j = 0; j < NL; ++j) wb[j][1] = LDSW(j, 5);
        }
#pragma unroll
        for (int nt = 0; nt < CNT; ++nt)
            acc[nt] = __builtin_amdgcn_mfma_f32_16x16x32_bf16(ha1, wf[nt][4], acc[nt], 0, 0, 0);
        if constexpr (NL > 0) {
#pragma unroll
            for (int j = 0; j < NL; ++j)
                accL[j] = __builtin_amdgcn_mfma_f32_16x16x32_bf16(ha1, wb[j][0], accL[j], 0, 0, 0);
        }
        if constexpr (MODE == 2) acc2 = __builtin_amdgcn_mfma_f32_16x16x32_bf16(ha1, wf2[4], acc2, 0, 0, 0);
        // kt = 5
        if constexpr (NL > 0) {
#pragma unroll
            for (int j = 0; j < NL; ++j) wb[j][0] = LDSW(j, 6);
        }
#pragma unroll
        for (int nt = 0; nt < CNT; ++nt)
            acc[nt] = __builtin_amdgcn_mfma_f32_16x16x32_bf16(ha2, wf[nt][5], acc[nt], 0, 0, 0);
        if constexpr (NL > 0) {
#pragma unroll
            for (int j = 0; j < NL; ++j)
                accL[j] = __builtin_amdgcn_mfma_f32_16x16x32_bf16(ha2, wb[j][1], accL[j], 0, 0, 0);
        }
        if constexpr (MODE == 2) acc2 = __builtin_amdgcn_mfma_f32_16x16x32_bf16(ha2, wf2[5], acc2, 0, 0, 0);
        // kt = 6
#pragma unroll
        for (int nt = 0; nt < CNT; ++nt)
            acc[nt] = __builtin_amdgcn_mfma_f32_16x16x32_bf16(ha0, wf[nt][6], acc[nt], 0, 0, 0);
        if constexpr (NL > 0) {
#pragma unroll
            for (int j = 0; j < NL; ++j)
                accL[j] = __builtin_amdgcn_mfma_f32_16x16x32_bf16(ha0, wb[j][0], accL[j], 0, 0, 0);
        }
        if constexpr (MODE == 2) acc2 = __builtin_amdgcn_mfma_f32_16x16x32_bf16(ha0, wf2[6], acc2, 0, 0, 0);

        // gate stores: lanes<16, stride-1 cols, conflict-free
        if (l < 16) {
#pragma unroll
            for (int nt = 0; nt < CNT; ++nt) {
                int col = (tile0 + nt) * 16 + l;
#pragma unroll
                for (int r = 0; r < 4; ++r) gbuf[r * G1P + col] = acc[nt][r];
            }
            if constexpr (NL > 0) {
#pragma unroll
                for (int j = 0; j < NL; ++j) {
                    int col = (39 + ls0 + j) * 16 + l;
#pragma unroll
                    for (int r = 0; r < 4; ++r) gbuf[r * G1P + col] = accL[j][r];
                }
            }
        }

        if constexpr (MODE == 1) asm volatile("s_waitcnt vmcnt(2)" ::: "memory");
        asm volatile("s_waitcnt lgkmcnt(0)" ::: "memory");
        __builtin_amdgcn_s_barrier(); // b1

        // layer-1 elementwise: wave -> (row rw, cols jbase..jbase+100) — verified
        {
            const float* gb = gbuf + rw * G1P + jbase;
            const u16* xr = xgs + (t & 1) * 3328 + rw * G1P + jbase;
            float p0[4], p1[4];
#pragma unroll
            for (int g = 0; g < 4; ++g) p0[g] = gb[g * 200 + l] + bfu2f(xr[g * 200 + l]);
#pragma unroll
            for (int g = 0; g < 4; ++g) p1[g] = gb[g * 200 + 64 + l] + bfu2f(xr[g * 200 + 64 + l]);
            {
                float gi = sig2(p0[0]), gf = sig2(p0[1]), gg = tanh2(p0[2]), go = sig2(p0[3]);
                creg0 = gf * creg0 + gi * gg;
                float h = go * tanh2(creg0);
                *(u16*)((char*)hbuf + ((rw * 448 + (jbase + l) * 2) ^ ((rw & 7) << 4))) = f2bf(h);
            }
            if (l < 36) {
                float gi = sig2(p1[0]), gf = sig2(p1[1]), gg = tanh2(p1[2]), go = sig2(p1[3]);
                creg1 = gf * creg1 + gi * gg;
                float h = go * tanh2(creg1);
                *(u16*)((char*)hbuf + ((rw * 448 + (jbase + 64 + l) * 2) ^ ((rw & 7) << 4))) = f2bf(h);
            }
        }

        asm volatile("s_waitcnt lgkmcnt(0)" ::: "memory");
        __builtin_amdgcn_s_barrier(); // b2
    }

    asm volatile("s_waitcnt vmcnt(0)" ::: "memory"); // drain dangling t=512 stage

    // epilogue (wave 7): layer-2 for steps 510 and 511 — verified
    if constexpr (MODE == 2) {
        L2EW(510);
        bf16x8 he = LDHB(0);
        acc2 = __builtin_amdgcn_mfma_f32_16x16x32_bf16(he, wf2[0], fz, 0, 0, 0);
        he = LDHB(1); acc2 = __builtin_amdgcn_mfma_f32_16x16x32_bf16(he, wf2[1], acc2, 0, 0, 0);
        he = LDHB(2); acc2 = __builtin_amdgcn_mfma_f32_16x16x32_bf16(he, wf2[2], acc2, 0, 0, 0);
        he = LDHB(3); acc2 = __builtin_amdgcn_mfma_f32_16x16x32_bf16(he, wf2[3], acc2, 0, 0, 0);
        he = LDHB(4); acc2 = __builtin_amdgcn_mfma_f32_16x16x32_bf16(he, wf2[4], acc2, 0, 0, 0);
        he = LDHB(5); acc2 = __builtin_amdgcn_mfma_f32_16x16x32_bf16(he, wf2[5], acc2, 0, 0, 0);
        he = LDHB(6); acc2 = __builtin_amdgcn_mfma_f32_16x16x32_bf16(he, wf2[6], acc2, 0, 0, 0);
        L2EW(511);
    }
}

__global__ __launch_bounds__(512, 2)
void lstm_main(const u16* __restrict__ xg,
               const u16* __restrict__ whhf,
               const float* __restrict__ w_ih2,
               const float* __restrict__ w_hh2,
               const float* __restrict__ b_ih2,
               const float* __restrict__ b_hh2,
               float* __restrict__ out) {
    __shared__ __align__(16) u16 hbuf[16 * KP];       //   7168 B, XOR-swizzled bf16 h
    __shared__ __align__(16) float gbuf[4 * G1P];     //  13312 B, gates [b][col]
    __shared__ __align__(16) u16 xgs[2 * 3328];       //  13312 B, staged xg (dbuf)
    __shared__ __align__(16) u16 wlds[11 * 7 * 512];  //  78848 B, B-frags: tiles 39-49
    // total 112,640 B -> 1 WG/CU -> occupancy ceiling 2 waves/SIMD -> 256-reg budget

    int tid = threadIdx.x, mw = blockIdx.x;
    int l = tid & 63, wv = tid >> 6;

    for (int i = tid; i < 16 * KP; i += 512) hbuf[i] = 0;
    // copy tiles 39..49 B-fragments into LDS (contiguous in whhf)
    {
        const uint4* src = (const uint4*)(whhf + (size_t)(39 * 7) * 512);
        uint4* dst = (uint4*)wlds;
        for (int i = tid; i < 4928; i += 512) dst[i] = src[i];
    }
    __syncthreads();

    // reg tiles: w0-w6 = 5 each (0-34), w7 = 4 (35-38); LDS tiles 39-49:
    // w0:{39,40} w1:{41,42} w2:{43,44} w3:{45,46} w4:{47} w5:{48} w6:{49}
    if (wv == 0)
        lstm_body<5, 2, 0>(0, 0, 0, l, mw, xg, whhf, w_ih2, w_hh2, b_ih2, b_hh2, out, hbuf, gbuf, xgs, wlds);
    else if (wv == 1)
        lstm_body<5, 2, 0>(5, 2, 1, l, mw, xg, whhf, w_ih2, w_hh2, b_ih2, b_hh2, out, hbuf, gbuf, xgs, wlds);
    else if (wv == 2)
        lstm_body<5, 2, 0>(10, 4, 2, l, mw, xg, whhf, w_ih2, w_hh2, b_ih2, b_hh2, out, hbuf, gbuf, xgs, wlds);
    else if (wv == 3)
        lstm_body<5, 2, 1>(15, 6, 3, l, mw, xg, whhf, w_ih2, w_hh2, b_ih2, b_hh2, out, hbuf, gbuf, xgs, wlds);
    else if (wv == 4)
        lstm_body<5, 1, 1>(20, 8, 4, l, mw, xg, whhf, w_ih2, w_hh2, b_ih2, b_hh2, out, hbuf, gbuf, xgs, wlds);
    else if (wv == 5)
        lstm_body<5, 1, 1>(25, 9, 5, l, mw, xg, whhf, w_ih2, w_hh2, b_ih2, b_hh2, out, hbuf, gbuf, xgs, wlds);
    else if (wv == 6)
        lstm_body<5, 1, 1>(30, 10, 6, l, mw, xg, whhf, w_ih2, w_hh2, b_ih2, b_hh2, out, hbuf, gbuf, xgs, wlds);
    else
        lstm_body<4, 0, 2>(35, 0, 7, l, mw, xg, whhf, w_ih2, w_hh2, b_ih2, b_hh2, out, hbuf, gbuf, xgs, wlds);
}

extern "C" void kernel_launch(void* const* d_in, const int* in_sizes, int n_in,
                              void* d_out, int out_size, void* d_ws, size_t ws_size,
                              hipStream_t stream) {
    const float* X = (const float*)d_in[0];
    const float* w_ih1 = (const float*)d_in[1];
    const float* w_hh1 = (const float*)d_in[2];
    const float* b_ih1 = (const float*)d_in[3];
    const float* b_hh1 = (const float*)d_in[4];
    const float* w_ih2 = (const float*)d_in[5];
    const float* w_hh2 = (const float*)d_in[6];
    const float* b_ih2 = (const float*)d_in[7];
    const float* b_hh2 = (const float*)d_in[8];
    float* out = (float*)d_out;

    char* ws = (char*)d_ws;
    size_t off = 0;
    u16* xg = (u16*)(ws + off);
    off += (size_t)512 * 256 * G1P * 2; // 218,103,808 B (natural layout)
    u16* whhf = (u16*)(ws + off);
    off += (size_t)22400 * 8 * 2; // 358,400 B (also absorbs t=512 stage overread)
    u16* wihf = (u16*)(ws + off);
    off += (size_t)13312 * 8 * 2; // 212,992 B
    float* b1p = (float*)(ws + off);
    off += G1P * 4;
    if (ws_size < off) return; // insufficient workspace -> visible failure

    repack_k<<<140, 256, 0, stream>>>(w_ih1, w_hh1, b_ih1, b_hh1, wihf, whhf, b1p);
    xg_gemm<<<2048, 256, 0, stream>>>(X, wihf, b1p, xg);
    lstm_main<<<64, 512, 0, stream>>>(xg, whhf, w_ih2, w_hh2, b_ih2, b_hh2, out);
}